// Round 2
// baseline (47064.883 us; speedup 1.0000x reference)
//
#include <hip/hip_runtime.h>

typedef unsigned short u16;
typedef __bf16 bf16x8 __attribute__((ext_vector_type(8)));
typedef float f32x4 __attribute__((ext_vector_type(4)));

#define EPSC 1e-6f

// ---------- helpers ----------
__device__ __forceinline__ float b2f(u16 x) { return __uint_as_float(((unsigned)x) << 16); }
__device__ __forceinline__ u16 f2b(float f) {
    unsigned u = __float_as_uint(f);
    unsigned r = (u + 0x7fffu + ((u >> 16) & 1u)) >> 16;
    return (u16)r;
}
__device__ __forceinline__ float softplusf(float x) {
    return fmaxf(x, 0.f) + log1pf(__expf(-fabsf(x)));
}

// ---------- conversion / transpose kernels ----------
__global__ void conv_x4(u16* __restrict__ dst, const float* __restrict__ x) {
    size_t i4 = (size_t)blockIdx.x * 256 + threadIdx.x;
    size_t o = i4 * 4;
    int d = (int)(o & 511);
    int b = (int)((o >> 9) & 255);
    int t = (int)(o >> 17);
    float4 v = *(const float4*)(x + ((size_t)b * 256 + t) * 512 + d);
    unsigned p0 = (unsigned)f2b(v.x) | ((unsigned)f2b(v.y) << 16);
    unsigned p1 = (unsigned)f2b(v.z) | ((unsigned)f2b(v.w) << 16);
    *(uint2*)(dst + o) = make_uint2(p0, p1);
}

__global__ void conv_f32_bf16(u16* __restrict__ dst, const float* __restrict__ src, int n) {
    int i = blockIdx.x * 256 + threadIdx.x;
    if (i < n) dst[i] = f2b(src[i]);
}

__global__ void tr_conv(u16* __restrict__ dst, const float* __restrict__ src,
                        int R, int C, int ld) {
    int idx = blockIdx.x * 256 + threadIdx.x;
    if (idx >= R * C) return;
    int c = idx / R, r = idx % R;
    dst[idx] = f2b(src[(size_t)r * ld + c]);
}

__global__ void init_ctr(unsigned* ctr) { if (threadIdx.x == 0) *ctr = 0u; }

// ---------- generic 128x128 bf16 MFMA GEMM (phase A/C) ----------
enum { EPI_PARTIAL = 0, EPI_BF16_RELU = 1, EPI_BF16_NONE = 2,
       EPI_F32_RELU = 3, EPI_F32_SP = 4, EPI_F32_SIG = 5 };

template <int EPI>
__global__ __launch_bounds__(256)
void gemm128(const u16* __restrict__ A0, const u16* __restrict__ A1,
             int lda0, int lda1, int kSplit,
             const u16* __restrict__ Wt, int ldw,
             const float* __restrict__ bias,
             u16* __restrict__ Cb, float* __restrict__ Cf,
             int M, int N, int K, int kChunk) {
    __shared__ __align__(16) u16 As[128 * 72];
    __shared__ __align__(16) u16 Bs[128 * 72];
    const int tid = threadIdx.x;
    const int wid = tid >> 6, lane = tid & 63;
    const int wm = wid >> 1, wn = wid & 1;
    const int lr = lane & 15, lk = lane >> 4;
    const int m0 = blockIdx.y * 128, n0 = blockIdx.x * 128;
    const int kBeg = blockIdx.z * kChunk;
    const int rsub = lane >> 3;
    const int csub = (lane & 7) * 8;

    f32x4 acc[4][4];
#pragma unroll
    for (int i = 0; i < 4; i++)
#pragma unroll
        for (int j = 0; j < 4; j++) { f32x4 z = {0.f, 0.f, 0.f, 0.f}; acc[i][j] = z; }

    for (int kt = 0; kt < kChunk; kt += 64) {
        const int k0 = kBeg + kt;
        const u16* Ap; int kk, lda;
        if (k0 < kSplit) { Ap = A0; kk = k0; lda = lda0; }
        else             { Ap = A1; kk = k0 - kSplit; lda = lda1; }
        uint4 ra[4], rb[4];
#pragma unroll
        for (int i = 0; i < 4; i++) {
            const int q = wid * 4 + i;
            const int r = q * 8 + rsub;
            ra[i] = *(const uint4*)(Ap + (size_t)(m0 + r) * lda + kk + csub);
            rb[i] = *(const uint4*)(Wt + (size_t)(n0 + r) * ldw + k0 + csub);
        }
        __syncthreads();
#pragma unroll
        for (int i = 0; i < 4; i++) {
            const int q = wid * 4 + i;
            const int r = q * 8 + rsub;
            *(uint4*)&As[r * 72 + csub] = ra[i];
            *(uint4*)&Bs[r * 72 + csub] = rb[i];
        }
        __syncthreads();
#pragma unroll
        for (int s = 0; s < 2; s++) {
            bf16x8 af[4], bfr[4];
#pragma unroll
            for (int i = 0; i < 4; i++)
                af[i] = *(const bf16x8*)&As[(wm * 64 + i * 16 + lr) * 72 + s * 32 + lk * 8];
#pragma unroll
            for (int j = 0; j < 4; j++)
                bfr[j] = *(const bf16x8*)&Bs[(wn * 64 + j * 16 + lr) * 72 + s * 32 + lk * 8];
#pragma unroll
            for (int i = 0; i < 4; i++)
#pragma unroll
                for (int j = 0; j < 4; j++)
                    acc[i][j] = __builtin_amdgcn_mfma_f32_16x16x32_bf16(af[i], bfr[j], acc[i][j], 0, 0, 0);
        }
    }

    const int rowb = m0 + wm * 64, colb = n0 + wn * 64;
#pragma unroll
    for (int i = 0; i < 4; i++) {
#pragma unroll
        for (int j = 0; j < 4; j++) {
            const int col = colb + j * 16 + lr;
#pragma unroll
            for (int r = 0; r < 4; r++) {
                const int row = rowb + i * 16 + lk * 4 + r;
                float v = acc[i][j][r];
                if (EPI == EPI_PARTIAL) {
                    Cf[(size_t)blockIdx.z * ((size_t)M * N) + (size_t)row * N + col] = v;
                } else {
                    if (bias) v += bias[col];
                    if (EPI == EPI_BF16_RELU || EPI == EPI_F32_RELU) v = fmaxf(v, 0.f);
                    else if (EPI == EPI_F32_SP)  v = softplusf(v);
                    else if (EPI == EPI_F32_SIG) v = 1.f / (1.f + __expf(-v));
                    if (EPI == EPI_BF16_RELU || EPI == EPI_BF16_NONE) Cb[(size_t)row * N + col] = f2b(v);
                    else Cf[(size_t)row * N + col] = v;
                }
            }
        }
    }
}

// ---------- workspace layout (bytes) ----------
static constexpr size_t oPHIXWT  = 0;
static constexpr size_t oWCATT   = oPHIXWT  + 1048576;
static constexpr size_t oEMW2T   = oWCATT   + 8388608;
static constexpr size_t oESW2T   = oEMW2T   + 262144;
static constexpr size_t oWIHPHIT = oESW2T   + 262144;
static constexpr size_t oWIHZT   = oWIHPHIT + 6291456;
static constexpr size_t oPMW1T   = oWIHZT   + 786432;
static constexpr size_t oPMW2T   = oPMW1T   + 2097152;
static constexpr size_t oPSW1T   = oPMW2T   + 262144;
static constexpr size_t oPSW2T   = oPSW1T   + 2097152;
static constexpr size_t oDMW1T   = oPSW2T   + 262144;
static constexpr size_t oDMW2T   = oDMW1T   + 2359296;
static constexpr size_t oXBFT    = oDMW2T   + 1048576;      // 64MB: XbfT, later gip0, later PMbuf
static constexpr size_t oPHI     = oXBFT    + 67108864;     // [T][B][H] bf16
static constexpr size_t oHS      = oPHI     + 134217728;    // [T+1][B][H] bf16
static constexpr size_t oZBF     = oHS      + 134742016;    // [T][B][Z] bf16
static constexpr size_t oGIP1    = oZBF     + 16777216;     // 50.3MB: gip1, later PSbuf
static constexpr size_t oT12     = oGIP1    + 50331648;     // [256][2048] bf16
static constexpr size_t oBAR     = oT12     + 1048576;
static constexpr size_t oKLDT    = oBAR     + 4096;
static constexpr size_t oNLLT    = oKLDT    + 1024;
static constexpr size_t WS_NEED  = oNLLT    + 1024;

static constexpr size_t NZ = (size_t)256 * 256 * 128;
static constexpr size_t O_Z  = 3;
static constexpr size_t O_MU = 3 + NZ;
static constexpr size_t O_STD = 3 + 2 * NZ;
static constexpr size_t O_XM = 3 + 3 * NZ;

// ---------- persistent-kernel building blocks ----------
__device__ __forceinline__ void gbar(unsigned* ctr, unsigned* nbar) {
    __syncthreads();
    if (threadIdx.x == 0) {
        const unsigned tgt = (++(*nbar)) * 256u;
        __threadfence();
        __hip_atomic_fetch_add(ctr, 1u, __ATOMIC_RELEASE, __HIP_MEMORY_SCOPE_AGENT);
        while (__hip_atomic_load(ctr, __ATOMIC_RELAXED, __HIP_MEMORY_SCOPE_AGENT) < tgt)
            __builtin_amdgcn_s_sleep(1);
        __threadfence();
    }
    __syncthreads();
}

template <int TM, int TN>
__device__ __forceinline__ void mm_tile(const u16* A0, const u16* A1,
                                        const int lda, const int kSplit,
                                        const u16* Bt, const int ldb,
                                        const int kBeg, const int kEnd,
                                        u16* As, u16* Bs, f32x4 (&acc)[TM/32][TN/32]) {
    const int tid = threadIdx.x;
    const int wid = tid >> 6, lane = tid & 63;
    const int wm = wid >> 1, wn = wid & 1;
    const int lr = lane & 15, lk = lane >> 4;
    const int sr = tid >> 3, sc = (tid & 7) * 8;
    for (int k0 = kBeg; k0 < kEnd; k0 += 64) {
        const u16* Ap; int kk;
        if (k0 < kSplit) { Ap = A0; kk = k0; } else { Ap = A1; kk = k0 - kSplit; }
        uint4 ra[TM/32], rb[TN/32];
#pragma unroll
        for (int i = 0; i < TM/32; i++)
            ra[i] = *(const uint4*)(Ap + (size_t)(i*32 + sr) * lda + kk + sc);
#pragma unroll
        for (int i = 0; i < TN/32; i++)
            rb[i] = *(const uint4*)(Bt + (size_t)(i*32 + sr) * ldb + k0 + sc);
        __syncthreads();
#pragma unroll
        for (int i = 0; i < TM/32; i++) *(uint4*)&As[(i*32 + sr) * 72 + sc] = ra[i];
#pragma unroll
        for (int i = 0; i < TN/32; i++) *(uint4*)&Bs[(i*32 + sr) * 72 + sc] = rb[i];
        __syncthreads();
#pragma unroll
        for (int s = 0; s < 2; s++) {
            bf16x8 af[TM/32], bfr[TN/32];
#pragma unroll
            for (int i = 0; i < TM/32; i++)
                af[i] = *(const bf16x8*)&As[(wm*(TM/2) + i*16 + lr) * 72 + s*32 + lk*8];
#pragma unroll
            for (int j = 0; j < TN/32; j++)
                bfr[j] = *(const bf16x8*)&Bs[(wn*(TN/2) + j*16 + lr) * 72 + s*32 + lk*8];
#pragma unroll
            for (int i = 0; i < TM/32; i++)
#pragma unroll
                for (int j = 0; j < TN/32; j++)
                    acc[i][j] = __builtin_amdgcn_mfma_f32_16x16x32_bf16(af[i], bfr[j], acc[i][j], 0, 0, 0);
        }
    }
}

// ---------- persistent sequential-phase kernel ----------
__global__ __launch_bounds__(256)
void vrnn_seq(const float* __restrict__ eps,
              const float* __restrict__ em_b1, const float* __restrict__ es_b1,
              const float* __restrict__ em_b2, const float* __restrict__ es_b2,
              const float* __restrict__ gbih, const float* __restrict__ gbhh,
              char* ws, float* out) {
    __shared__ __align__(16) u16 SA[128 * 72];
    __shared__ __align__(16) u16 SB[128 * 72];
    __shared__ float zmL[512], zsL[512];

    const int bx = blockIdx.x, tid = threadIdx.x;
    const int wid = tid >> 6, lane = tid & 63;
    const int lr = lane & 15, lk = lane >> 4;
    const int wm = wid >> 1, wn = wid & 1;

    const u16* wcatT   = (const u16*)(ws + oWCATT);
    const u16* emW2T   = (const u16*)(ws + oEMW2T);
    const u16* esW2T   = (const u16*)(ws + oESW2T);
    const u16* wihPhiT = (const u16*)(ws + oWIHPHIT);
    const u16* wihZT   = (const u16*)(ws + oWIHZT);
    const u16* PHI     = (const u16*)(ws + oPHI);
    u16* HS   = (u16*)(ws + oHS);
    u16* ZBFg = (u16*)(ws + oZBF);
    u16* T12g = (u16*)(ws + oT12);
    u16* gip0 = (u16*)(ws + oXBFT);
    u16* gip1 = (u16*)(ws + oGIP1);
    unsigned* ctr = (unsigned*)(ws + oBAR);

    float* outZ  = out + O_Z;
    float* outMu = out + O_MU;
    float* outSd = out + O_STD;

    unsigned nbar = 0;
    f32x4 gacc[4][4];

    // ---- prologue: chunk-0 GIP (phi @ gru_wih[:H]) : 1536 tiles of 128x128, 6 per block ----
#pragma unroll 1
    for (int i = 0; i < 6; i++) {
        const int tg = bx * 6 + i;
        const int mI = tg / 24, nI = tg % 24;
#pragma unroll
        for (int a = 0; a < 4; a++)
#pragma unroll
            for (int b = 0; b < 4; b++) { f32x4 z = {0.f,0.f,0.f,0.f}; gacc[a][b] = z; }
        const u16* Ab = PHI + (size_t)(mI * 128) * 1024;
        mm_tile<128,128>(Ab, Ab, 1024, 0x40000000, wihPhiT + (size_t)(nI*128)*1024, 1024,
                         0, 1024, SA, SB, gacc);
        u16* C = gip0 + (size_t)(mI * 128) * 3072 + nI * 128;
#pragma unroll
        for (int a = 0; a < 4; a++)
#pragma unroll
            for (int b = 0; b < 4; b++)
#pragma unroll
                for (int r = 0; r < 4; r++)
                    C[(size_t)(wm*64 + a*16 + lk*4 + r) * 3072 + wn*64 + b*16 + lr] = f2b(gacc[a][b][r]);
    }
    gbar(ctr, &nbar);

    // ---- 256 sequential steps, 3 windows each ----
#pragma unroll 1
    for (int t = 0; t < 256; t++) {
        const int c = t >> 5, k = t & 31;
        const u16* gip_cur = (c & 1) ? gip1 : gip0;
        u16* gip_nxt = (c & 1) ? gip0 : gip1;

        // ======== window 1: T12 = [h_t | phi_t] @ wcat  (blocks 0..127, 64x64 tiles) ========
        if (bx < 128) {
            const int mI = bx & 3, nI = bx >> 2;
            f32x4 acc[2][2];
#pragma unroll
            for (int a = 0; a < 2; a++)
#pragma unroll
                for (int b = 0; b < 2; b++) { f32x4 z = {0.f,0.f,0.f,0.f}; acc[a][b] = z; }
            mm_tile<64,64>(HS + (size_t)t*262144 + (size_t)(mI*64)*1024,
                           PHI + (size_t)t*262144 + (size_t)(mI*64)*1024,
                           1024, 1024,
                           wcatT + (size_t)(nI*64)*2048, 2048, 0, 2048, SA, SB, acc);
#pragma unroll
            for (int a = 0; a < 2; a++)
#pragma unroll
                for (int b = 0; b < 2; b++) {
                    const int col = nI*64 + wn*32 + b*16 + lr;
                    const float bb = (col < 1024) ? em_b1[col] : es_b1[col - 1024];
#pragma unroll
                    for (int r = 0; r < 4; r++) {
                        const int row = mI*64 + wm*32 + a*16 + lk*4 + r;
                        T12g[(size_t)row*2048 + col] = f2b(fmaxf(acc[a][b][r] + bb, 0.f));
                    }
                }
        }
        gbar(ctr, &nbar);

        // ======== window 2: zm/zs/z (blocks 0..63) | GIP quarter (blocks 128..255) ========
        if (bx < 64) {
            const int rg = bx >> 2, cq = bx & 3, r0 = rg * 16;
            const int half = wid >> 1, jt = cq*2 + (wid & 1);  // ntile 0..7 of 128 cols
            const u16* W = ((half ? esW2T : emW2T) + (size_t)(jt*16 + lr) * 1024);
            const u16* Arow = T12g + (size_t)(r0 + lr) * 2048 + half * 1024;
            f32x4 a4 = {0.f,0.f,0.f,0.f};
#pragma unroll 8
            for (int ks = 0; ks < 32; ks++) {
                bf16x8 af = *(const bf16x8*)(Arow + ks*32 + lk*8);
                bf16x8 bf = *(const bf16x8*)(W + ks*32 + lk*8);
                a4 = __builtin_amdgcn_mfma_f32_16x16x32_bf16(af, bf, a4, 0, 0, 0);
            }
            const int colg = jt*16 + lr;            // 0..127
            const int cl = colg & 31;               // block-local col
            float* dstL = half ? zsL : zmL;
#pragma unroll
            for (int r = 0; r < 4; r++) {
                const int m = lk*4 + r;
                float v = a4[r];
                if (!half) dstL[m*32 + cl] = fmaxf(v + em_b2[colg], 0.f);
                else       dstL[m*32 + cl] = softplusf(v + es_b2[colg]);
            }
            __syncthreads();
            for (int e = tid; e < 512; e += 256) {
                const int rr = e >> 5, cc = e & 31;
                const int colz = cq*32 + cc;
                const float zm = zmL[e], zs = zsL[e];
                const size_t o = (size_t)t*32768 + (size_t)(r0 + rr)*128 + colz;
                const float z = zm + zs * eps[o];
                outMu[o] = zm; outSd[o] = zs; outZ[o] = z;
                ZBFg[o] = f2b(z);
            }
        } else if (bx >= 128 && c + 1 < 8) {
            const int wq = k*2;                     // window-2 slot
            const int tl = wq >> 2, q = wq & 3;
            if (tl < 12) {
                const int tg = tl*128 + (bx - 128);
                const int mI = tg / 24, nI = tg % 24;
                if (q == 0) {
#pragma unroll
                    for (int a = 0; a < 4; a++)
#pragma unroll
                        for (int b = 0; b < 4; b++) { f32x4 z = {0.f,0.f,0.f,0.f}; gacc[a][b] = z; }
                }
                const u16* Ab = PHI + ((size_t)(c+1)*8192 + (size_t)(mI*128)) * 1024;
                mm_tile<128,128>(Ab, Ab, 1024, 0x40000000, wihPhiT + (size_t)(nI*128)*1024, 1024,
                                 q*256, q*256 + 256, SA, SB, gacc);
                if (q == 3) {
                    u16* C = gip_nxt + (size_t)(mI*128)*3072 + nI*128;
#pragma unroll
                    for (int a = 0; a < 4; a++)
#pragma unroll
                        for (int b = 0; b < 4; b++)
#pragma unroll
                            for (int r = 0; r < 4; r++)
                                C[(size_t)(wm*64 + a*16 + lk*4 + r)*3072 + wn*64 + b*16 + lr] = f2b(gacc[a][b][r]);
                }
            }
        }
        gbar(ctr, &nbar);

        // ======== window 3: GRU -> h_{t+1} (blocks 0..127) | GIP quarter (128..255) ========
        if (bx < 128) {
            const int rg = bx >> 3, q = bx & 7, r0 = rg * 16;
            bf16x8 zf[4];
            const u16* zrow = ZBFg + (size_t)t*32768 + (size_t)(r0 + lr)*128;
#pragma unroll
            for (int ks = 0; ks < 4; ks++) zf[ks] = *(const bf16x8*)(zrow + ks*32 + lk*8);
            const u16* gipb = gip_cur + (size_t)(k*256)*3072;
            u16* HSn = HS + (size_t)(t+1)*262144;
#pragma unroll
            for (int jj = 0; jj < 2; jj++) {
                const int jt = q*8 + wid*2 + jj;    // 0..63
                const int col = jt*16 + lr;         // 0..1023
                f32x4 aR = {0.f,0.f,0.f,0.f}, aU = {0.f,0.f,0.f,0.f}, aN = {0.f,0.f,0.f,0.f};
#pragma unroll
                for (int ks = 0; ks < 4; ks++) {
                    const int ko = ks*32 + lk*8;
                    bf16x8 bR = *(const bf16x8*)(wihZT + (size_t)(       jt*16 + lr)*128 + ko);
                    bf16x8 bU = *(const bf16x8*)(wihZT + (size_t)(1024 + jt*16 + lr)*128 + ko);
                    bf16x8 bN = *(const bf16x8*)(wihZT + (size_t)(2048 + jt*16 + lr)*128 + ko);
                    aR = __builtin_amdgcn_mfma_f32_16x16x32_bf16(zf[ks], bR, aR, 0, 0, 0);
                    aU = __builtin_amdgcn_mfma_f32_16x16x32_bf16(zf[ks], bU, aU, 0, 0, 0);
                    aN = __builtin_amdgcn_mfma_f32_16x16x32_bf16(zf[ks], bN, aN, 0, 0, 0);
                }
                const float bihR = gbih[col],        bR_ = gbhh[col];
                const float bihU = gbih[1024 + col], bU_ = gbhh[1024 + col];
                const float bihN = gbih[2048 + col], bN_ = gbhh[2048 + col];
#pragma unroll
                for (int r = 0; r < 4; r++) {
                    const int b = r0 + lk*4 + r;
                    const u16* gp = gipb + (size_t)b*3072;
                    const float gr = aR[r] + b2f(gp[col])        + bihR + bR_;
                    const float gu = aU[r] + b2f(gp[1024 + col]) + bihU + bU_;
                    float gn       = aN[r] + b2f(gp[2048 + col]) + bihN;
                    const float rr_ = 1.f / (1.f + __expf(-gr));
                    const float uu  = 1.f / (1.f + __expf(-gu));
                    gn += rr_ * bN_;
                    const float e2 = __expf(-2.f * fabsf(gn));
                    float th = (1.f - e2) / (1.f + e2);
                    th = (gn < 0.f) ? -th : th;
                    HSn[(size_t)b*1024 + col] = f2b((1.f - uu) * th);
                }
            }
        } else if (c + 1 < 8) {
            const int wq = k*2 + 1;                 // window-3 slot
            const int tl = wq >> 2, q = wq & 3;
            if (tl < 12) {
                const int tg = tl*128 + (bx - 128);
                const int mI = tg / 24, nI = tg % 24;
                if (q == 0) {
#pragma unroll
                    for (int a = 0; a < 4; a++)
#pragma unroll
                        for (int b = 0; b < 4; b++) { f32x4 z = {0.f,0.f,0.f,0.f}; gacc[a][b] = z; }
                }
                const u16* Ab = PHI + ((size_t)(c+1)*8192 + (size_t)(mI*128)) * 1024;
                mm_tile<128,128>(Ab, Ab, 1024, 0x40000000, wihPhiT + (size_t)(nI*128)*1024, 1024,
                                 q*256, q*256 + 256, SA, SB, gacc);
                if (q == 3) {
                    u16* C = gip_nxt + (size_t)(mI*128)*3072 + nI*128;
#pragma unroll
                    for (int a = 0; a < 4; a++)
#pragma unroll
                        for (int b = 0; b < 4; b++)
#pragma unroll
                            for (int r = 0; r < 4; r++)
                                C[(size_t)(wm*64 + a*16 + lk*4 + r)*3072 + wn*64 + b*16 + lr] = f2b(gacc[a][b][r]);
                }
            }
        }
        gbar(ctr, &nbar);
    }
}

// ---------- loss ----------
__global__ __launch_bounds__(256)
void loss_per_t(const float* __restrict__ x,
                const float* __restrict__ xm,
                const float* __restrict__ zm, const float* __restrict__ zs,
                const float* __restrict__ pm, const float* __restrict__ ps,
                float* __restrict__ kldT, float* __restrict__ nllT) {
    const int t = blockIdx.x, bb = threadIdx.x;
    float kld = 0.f, nll = 0.f;
    const size_t ozb = ((size_t)t * 256 + bb) * 128;
    for (int zz = 0; zz < 128; zz++) {
        const float qs = zs[ozb + zz], qm = zm[ozb + zz];
        const float pmv = pm[ozb + zz], psv = ps[ozb + zz];
        const float d = qm - pmv;
        kld += logf(psv + EPSC) - logf(qs + EPSC)
             + (qs * qs + d * d) / (2.f * psv * psv + EPSC) - 0.5f;
    }
    const size_t oxb = ((size_t)t * 256 + bb) * 512;
    const size_t oxi = ((size_t)bb * 256 + t) * 512;
    for (int dd = 0; dd < 512; dd++) {
        const float xv = x[oxi + dd];
        float m = xm[oxb + dd];
        m = fminf(fmaxf(m, 1e-6f), 1.f - 1e-6f);
        nll -= xv * logf(m) + (1.f - xv) * log1pf(-m);
    }
    __shared__ float sk[256], sn[256];
    sk[bb] = kld; sn[bb] = nll;
    __syncthreads();
    for (int s = 128; s > 0; s >>= 1) {
        if (bb < s) { sk[bb] += sk[bb + s]; sn[bb] += sn[bb + s]; }
        __syncthreads();
    }
    if (bb == 0) { kldT[t] = sk[0] / 256.f; nllT[t] = sn[0] / 256.f; }
}

__global__ __launch_bounds__(256)
void loss_final(const float* __restrict__ kldT, const float* __restrict__ nllT,
                float* __restrict__ out) {
    const int tid = threadIdx.x;
    __shared__ float s[256];
    s[tid] = kldT[tid] + nllT[tid];
    __syncthreads();
    for (int st = 128; st > 0; st >>= 1) {
        if (tid < st) s[tid] += s[tid + st];
        __syncthreads();
    }
    if (tid == 0) { out[0] = s[0]; out[1] = kldT[255]; out[2] = nllT[255]; }
}

extern "C" void kernel_launch(void* const* d_in, const int* in_sizes, int n_in,
                              void* d_out, int out_size, void* d_ws, size_t ws_size,
                              hipStream_t stream) {
    const float* x      = (const float*)d_in[0];
    const float* eps    = (const float*)d_in[1];
    const float* h0     = (const float*)d_in[2];
    const float* phix_w = (const float*)d_in[3];
    const float* phix_b = (const float*)d_in[4];
    const float* pm_w1  = (const float*)d_in[5];
    const float* pm_b1  = (const float*)d_in[6];
    const float* pm_w2  = (const float*)d_in[7];
    const float* pm_b2  = (const float*)d_in[8];
    const float* ps_w1  = (const float*)d_in[9];
    const float* ps_b1  = (const float*)d_in[10];
    const float* ps_w2  = (const float*)d_in[11];
    const float* ps_b2  = (const float*)d_in[12];
    const float* em_w1  = (const float*)d_in[13];
    const float* em_b1  = (const float*)d_in[14];
    const float* em_w2  = (const float*)d_in[15];
    const float* em_b2  = (const float*)d_in[16];
    const float* es_w1  = (const float*)d_in[17];
    const float* es_b1  = (const float*)d_in[18];
    const float* es_w2  = (const float*)d_in[19];
    const float* es_b2  = (const float*)d_in[20];
    const float* dm_w1  = (const float*)d_in[21];
    const float* dm_b1  = (const float*)d_in[22];
    const float* dm_w2  = (const float*)d_in[23];
    const float* dm_b2  = (const float*)d_in[24];
    const float* gwih   = (const float*)d_in[25];
    const float* gbih   = (const float*)d_in[26];
    const float* gbhh   = (const float*)d_in[27];
    float* out = (float*)d_out;

    if (ws_size < WS_NEED) return;
    char* w = (char*)d_ws;
    u16* phixWt  = (u16*)(w + oPHIXWT);
    u16* wcatT   = (u16*)(w + oWCATT);
    u16* emW2T   = (u16*)(w + oEMW2T);
    u16* esW2T   = (u16*)(w + oESW2T);
    u16* wihPhiT = (u16*)(w + oWIHPHIT);
    u16* wihZT   = (u16*)(w + oWIHZT);
    u16* pmW1T   = (u16*)(w + oPMW1T);
    u16* pmW2T   = (u16*)(w + oPMW2T);
    u16* psW1T   = (u16*)(w + oPSW1T);
    u16* psW2T   = (u16*)(w + oPSW2T);
    u16* dmW1T   = (u16*)(w + oDMW1T);
    u16* dmW2T   = (u16*)(w + oDMW2T);
    u16* XbfT    = (u16*)(w + oXBFT);
    u16* PHI     = (u16*)(w + oPHI);
    u16* HS      = (u16*)(w + oHS);
    u16* ZBF     = (u16*)(w + oZBF);
    unsigned* ctr = (unsigned*)(w + oBAR);
    float* PMbuf = (float*)(w + oXBFT);
    float* PSbuf = (float*)(w + oGIP1);
    float* kldT  = (float*)(w + oKLDT);
    float* nllT  = (float*)(w + oNLLT);

    // ---- phase A: conversions / weight transposes / big precompute GEMMs ----
    conv_x4<<<32768, 256, 0, stream>>>(XbfT, x);
    conv_f32_bf16<<<1024, 256, 0, stream>>>(HS, h0, 262144);
    tr_conv<<<2048, 256, 0, stream>>>(phixWt, phix_w, 512, 1024, 1024);
    tr_conv<<<8192, 256, 0, stream>>>(wcatT, em_w1, 2048, 1024, 1024);
    tr_conv<<<8192, 256, 0, stream>>>(wcatT + (size_t)1024 * 2048, es_w1, 2048, 1024, 1024);
    tr_conv<<<512, 256, 0, stream>>>(emW2T, em_w2, 1024, 128, 128);
    tr_conv<<<512, 256, 0, stream>>>(esW2T, es_w2, 1024, 128, 128);
    tr_conv<<<12288, 256, 0, stream>>>(wihPhiT, gwih, 1024, 3072, 3072);
    tr_conv<<<1536, 256, 0, stream>>>(wihZT, gwih + (size_t)1024 * 3072, 128, 3072, 3072);
    tr_conv<<<4096, 256, 0, stream>>>(pmW1T, pm_w1, 1024, 1024, 1024);
    tr_conv<<<512, 256, 0, stream>>>(pmW2T, pm_w2, 1024, 128, 128);
    tr_conv<<<4096, 256, 0, stream>>>(psW1T, ps_w1, 1024, 1024, 1024);
    tr_conv<<<512, 256, 0, stream>>>(psW2T, ps_w2, 1024, 128, 128);
    tr_conv<<<4608, 256, 0, stream>>>(dmW1T, dm_w1, 1152, 1024, 1024);
    tr_conv<<<2048, 256, 0, stream>>>(dmW2T, dm_w2, 1024, 512, 512);

    // PHI = relu(x_t @ phix_w + b)  [T*B, 1024]
    gemm128<EPI_BF16_RELU><<<dim3(8, 512, 1), 256, 0, stream>>>(
        XbfT, nullptr, 512, 0, 512, phixWt, 512, phix_b, PHI, nullptr, 65536, 1024, 512, 512);

    // ---- phase B: persistent sequential kernel ----
    init_ctr<<<1, 64, 0, stream>>>(ctr);
    vrnn_seq<<<256, 256, 0, stream>>>(eps, em_b1, es_b1, em_b2, es_b2, gbih, gbhh,
                                      (char*)d_ws, out);

    // ---- phase C: deferred prior / decoder / loss ----
    gemm128<EPI_BF16_RELU><<<dim3(8, 512, 1), 256, 0, stream>>>(
        HS, nullptr, 1024, 0, 1024, pmW1T, 1024, pm_b1, PHI, nullptr, 65536, 1024, 1024, 1024);
    gemm128<EPI_F32_RELU><<<dim3(1, 512, 1), 256, 0, stream>>>(
        PHI, nullptr, 1024, 0, 1024, pmW2T, 1024, pm_b2, nullptr, PMbuf, 65536, 128, 1024, 1024);
    gemm128<EPI_BF16_RELU><<<dim3(8, 512, 1), 256, 0, stream>>>(
        HS, nullptr, 1024, 0, 1024, psW1T, 1024, ps_b1, PHI, nullptr, 65536, 1024, 1024, 1024);
    gemm128<EPI_F32_SP><<<dim3(1, 512, 1), 256, 0, stream>>>(
        PHI, nullptr, 1024, 0, 1024, psW2T, 1024, ps_b2, nullptr, PSbuf, 65536, 128, 1024, 1024);
    gemm128<EPI_BF16_RELU><<<dim3(8, 512, 1), 256, 0, stream>>>(
        HS, ZBF, 1024, 128, 1024, dmW1T, 1152, dm_b1, PHI, nullptr, 65536, 1024, 1152, 1152);
    gemm128<EPI_F32_SIG><<<dim3(4, 512, 1), 256, 0, stream>>>(
        PHI, nullptr, 1024, 0, 1024, dmW2T, 1024, dm_b2, nullptr, out + O_XM, 65536, 512, 1024, 1024);

    loss_per_t<<<256, 256, 0, stream>>>(x, out + O_XM, out + O_MU, out + O_STD,
                                        PMbuf, PSbuf, kldT, nllT);
    loss_final<<<1, 256, 0, stream>>>(kldT, nllT, out);
}